// Round 8
// baseline (114.068 us; speedup 1.0000x reference)
//
#include <hip/hip_runtime.h>
#include <math.h>

#define NT 512      // 8 waves, single block, single CU
#define EPT 8       // NT*EPT = 4096
#define NN 4096
#define MM 9
#define NIT 50

#define LAM  3.90625e-3f        // 2^-8 (per-thread carry decay)
#define LAM2 1.52587890625e-5f  // 2^-16
#define K1LAST 0.3333282470703125f
#define HALF8 3.90625e-3f       // 0.5^8

// ---------- DPP cross-lane helpers (VALU pipe, no LDS) ----------
template<int CTRL, int RMASK>
__device__ __forceinline__ float dpp_add(float v) {
  int m = __builtin_amdgcn_update_dpp(0, __builtin_bit_cast(int, v), CTRL, RMASK, 0xf, false);
  return v + __builtin_bit_cast(float, m);
}
// full-wave sum; total lands in lane 63
__device__ __forceinline__ float wave_sum(float v) {
  v = dpp_add<0x111, 0xf>(v);   // row_shr:1
  v = dpp_add<0x112, 0xf>(v);   // row_shr:2
  v = dpp_add<0x114, 0xf>(v);   // row_shr:4
  v = dpp_add<0x118, 0xf>(v);   // row_shr:8
  v = dpp_add<0x142, 0xa>(v);   // row_bcast:15 -> rows 1,3
  v = dpp_add<0x143, 0xc>(v);   // row_bcast:31 -> rows 2,3
  return v;
}
// broadcast lane l (uniform literal) -> SGPR
__device__ __forceinline__ float bcast_lane(float v, int l) {
  return __builtin_bit_cast(float, __builtin_amdgcn_readlane(__builtin_bit_cast(int, v), l));
}

// ---------- cyclic tridiagonal solve M p = r ----------
// M = 25I - 10(P+P^T) = 5(2I-S+)(2I-S-). Local scans + seed publish; after the
// barrier, carries for SELF and both NEIGHBOR THREADS reconstructed from a
// 9-wide seed window. Truncation ~2^-24 (vs 3.6e-2 tol).
__device__ __forceinline__ void solveM_pre(const float r[EPT], float pl0[EPT],
                                           float2* __restrict__ s_sc, int t) {
  float yl[EPT];
  yl[EPT - 1] = r[EPT - 1] * 0.1f;
#pragma unroll
  for (int j = EPT - 2; j >= 0; --j) yl[j] = fmaf(0.5f, yl[j + 1], r[j] * 0.1f);
  pl0[0] = 0.5f * yl[0];
#pragma unroll
  for (int j = 1; j < EPT; ++j) pl0[j] = 0.5f * (yl[j] + pl0[j - 1]);
  s_sc[t] = make_float2(yl[0], pl0[EPT - 1]);
}

// window g[k] = s_sc[t-4+k], k=0..8
__device__ __forceinline__ void gather9(const float2* __restrict__ s_sc, int t, float2 g[9]) {
#pragma unroll
  for (int k = 0; k < 9; ++k) g[k] = s_sc[(t + k - 4) & (NT - 1)];
}

__device__ __forceinline__ void carries_own(const float2 g[9], float& c, float& c2) {
  c = fmaf(LAM2, g[7].x, fmaf(LAM, g[6].x, g[5].x));
  float s1 = fmaf(LAM2, g[1].y, fmaf(LAM, g[2].y, g[3].y));
  float s2 = g[4].x;
  s2 = fmaf(LAM, g[3].x + g[5].x, s2);
  s2 = fmaf(LAM2, g[2].x + g[6].x, s2);
  c2 = fmaf(K1LAST, s2, s1);
}

__device__ __forceinline__ void finish_own(const float2 g[9], const float pl0[EPT], float p[EPT]) {
  const float K1[EPT] = {0.001953125f, 0.0048828125f, 0.01025390625f, 0.020751953125f,
                         0.0416259765625f, 0.08331298828125f, 0.166656494140625f,
                         K1LAST};
  float c, c2;
  carries_own(g, c, c2);
  float f2 = 0.5f;
#pragma unroll
  for (int j = 0; j < EPT; ++j) {
    p[j] = fmaf(c2, f2, fmaf(c, K1[j], pl0[j]));
    f2 *= 0.5f;
  }
}

// neighbor t-1's p[7]  (bit-identical to what thread t-1 computes)
__device__ __forceinline__ float p7_prev(const float2 g[9]) {
  float c = fmaf(LAM2, g[6].x, fmaf(LAM, g[5].x, g[4].x));
  float s1 = fmaf(LAM2, g[0].y, fmaf(LAM, g[1].y, g[2].y));
  float s2 = g[3].x;
  s2 = fmaf(LAM, g[2].x + g[4].x, s2);
  s2 = fmaf(LAM2, g[1].x + g[5].x, s2);
  float c2 = fmaf(K1LAST, s2, s1);
  return fmaf(c2, HALF8, fmaf(c, K1LAST, g[3].y));
}

// neighbor t+1's p[0]  (bit-identical to what thread t+1 computes)
__device__ __forceinline__ float p0_next(const float2 g[9]) {
  float c = fmaf(LAM2, g[8].x, fmaf(LAM, g[7].x, g[6].x));
  float s1 = fmaf(LAM2, g[2].y, fmaf(LAM, g[3].y, g[4].y));
  float s2 = g[5].x;
  s2 = fmaf(LAM, g[4].x + g[6].x, s2);
  s2 = fmaf(LAM2, g[3].x + g[7].x, s2);
  float c2 = fmaf(K1LAST, s2, s1);
  return fmaf(c2, 0.5f, fmaf(c, 0.001953125f, 0.5f * g[5].x));
}

__global__ void __launch_bounds__(NT, 2)
admm_kernel(const float* __restrict__ tg, const float* __restrict__ Ag,
            const float* __restrict__ x0, float* __restrict__ out) {
  __shared__ float2 s_sc[2][NT];                  // seed ping-pong (parity)
  __shared__ __align__(16) float s_wq[2][8][12];  // per-wave 9-partials (parity)
  __shared__ float s_S[MM * MM];
  __shared__ float s_L[MM * MM];
  __shared__ float s_gh7[NT][MM];                 // GH[m][7] per thread (stride 9: conflict-free)
  __shared__ float s_gh0[NT][MM];                 // GH[m][0] per thread

  const int t = threadIdx.x;
  const int base = t * EPT;
  const int lane = t & 63, wave = t >> 6;

  // ---- load A slice (register-resident; all accesses compile-time-indexed) ----
  float A[MM][EPT];
#pragma unroll
  for (int m = 0; m < MM; ++m) {
    float4 a0 = *(const float4*)(Ag + m * NN + base);
    float4 a1 = *(const float4*)(Ag + m * NN + base + 4);
    A[m][0] = a0.x; A[m][1] = a0.y; A[m][2] = a0.z; A[m][3] = a0.w;
    A[m][4] = a1.x; A[m][5] = a1.y; A[m][6] = a1.z; A[m][7] = a1.w;
  }

  // ---- load x0, target ----
  float x[EPT], tgt[EPT];
  {
    float4 v0 = *(const float4*)(x0 + base);
    float4 v1 = *(const float4*)(x0 + base + 4);
    x[0] = v0.x; x[1] = v0.y; x[2] = v0.z; x[3] = v0.w;
    x[4] = v1.x; x[5] = v1.y; x[6] = v1.z; x[7] = v1.w;
    float4 t0 = *(const float4*)(tg + base);
    float4 t1 = *(const float4*)(tg + base + 4);
    tgt[0] = t0.x; tgt[1] = t0.y; tgt[2] = t0.z; tgt[3] = t0.w;
    tgt[4] = t1.x; tgt[5] = t1.y; tgt[6] = t1.z; tgt[7] = t1.w;
  }
  float xm1_0 = x0[(base + NN - 1) & (NN - 1)];   // x0's left neighbor (global)

  // ---- b = A @ target: DPP reduce + lane-combine + readlane -> SGPRs ----
  float pq[MM];
#pragma unroll
  for (int m = 0; m < MM; ++m) {
    float s = 0.f;
#pragma unroll
    for (int j = 0; j < EPT; ++j) s = fmaf(A[m][j], tgt[j], s);
    pq[m] = wave_sum(s);
  }
  if (lane == 63) {
    *(float4*)&s_wq[0][wave][0] = make_float4(pq[0], pq[1], pq[2], pq[3]);
    *(float4*)&s_wq[0][wave][4] = make_float4(pq[4], pq[5], pq[6], pq[7]);
    s_wq[0][wave][8] = pq[8];
  }
  __syncthreads();
  float bb[MM];
  {
    float zv = 0.f;
    if (lane < MM) {
#pragma unroll
      for (int wv = 0; wv < 8; ++wv) zv += s_wq[0][wv][lane];
    }
#pragma unroll
    for (int m = 0; m < MM; ++m) bb[m] = bcast_lane(zv, m);
  }
  float bA[EPT];
#pragma unroll
  for (int j = 0; j < EPT; ++j) {
    float s = 0.f;
#pragma unroll
    for (int m = 0; m < MM; ++m) s = fmaf(bb[m], A[m][j], s);
    bA[j] = s;
  }

  // ---- S = I9 + A M^-1 A^T, keeping G columns for the GH fold ----
  float G[MM][EPT];
#pragma unroll
  for (int mc = 0; mc < MM; ++mc) {
    float rin[EPT];
#pragma unroll
    for (int j = 0; j < EPT; ++j) rin[j] = A[mc][j];
    float pl0[EPT];
    solveM_pre(rin, pl0, &s_sc[mc & 1][0], t);
    __syncthreads();
    float2 g[9];
    gather9(&s_sc[mc & 1][0], t, g);
    float gcol[EPT];
    finish_own(g, pl0, gcol);
#pragma unroll
    for (int j = 0; j < EPT; ++j) G[mc][j] = gcol[j];
#pragma unroll
    for (int k = 0; k < MM; ++k) {
      float s = 0.f;
#pragma unroll
      for (int j = 0; j < EPT; ++j) s = fmaf(A[k][j], gcol[j], s);
      pq[k] = wave_sum(s);
    }
    if (lane == 63) {
      *(float4*)&s_wq[0][wave][0] = make_float4(pq[0], pq[1], pq[2], pq[3]);
      *(float4*)&s_wq[0][wave][4] = make_float4(pq[4], pq[5], pq[6], pq[7]);
      s_wq[0][wave][8] = pq[8];
    }
    __syncthreads();
    if (wave == 0 && lane < MM) {
      float s = 0.f;
#pragma unroll
      for (int wv = 0; wv < 8; ++wv) s += s_wq[0][wv][lane];
      s_S[lane * MM + mc] = s + ((lane == mc) ? 1.f : 0.f);
    }
  }

  // ---- Sinv (Gauss-Jordan) + Cholesky Sinv = L L^T, fused on wave 0 ----
  if (t < 64) {
    float row[2 * MM];
#pragma unroll
    for (int j = 0; j < MM; ++j) row[j] = (t < MM) ? s_S[t * MM + j] : 0.f;
#pragma unroll
    for (int j = 0; j < MM; ++j) row[MM + j] = (j == t) ? 1.f : 0.f;
#pragma unroll
    for (int pp = 0; pp < MM; ++pp) {
      float pr[2 * MM];
#pragma unroll
      for (int j = 0; j < 2 * MM; ++j) pr[j] = __shfl(row[j], pp, 64);
      float rpiv = 1.f / pr[pp];
      float fct = row[pp] * rpiv;
#pragma unroll
      for (int j = 0; j < 2 * MM; ++j)
        row[j] = (t == pp) ? pr[j] * rpiv : fmaf(-fct, pr[j], row[j]);
    }
    float crow[MM];
#pragma unroll
    for (int j = 0; j < MM; ++j) crow[j] = row[MM + j];
#pragma unroll
    for (int k = 0; k < MM; ++k) {
      float dk = __shfl(crow[k], k, 64);
      float inv = 1.f / sqrtf(dk);
      crow[k] *= inv;
#pragma unroll
      for (int jj = k + 1; jj < MM; ++jj) {
        float ljk = __shfl(crow[k], jj, 64);   // L[jj][k]
        crow[jj] = fmaf(-crow[k], ljk, crow[jj]);
      }
    }
    if (t < MM) {
#pragma unroll
      for (int j = 0; j < MM; ++j) s_L[t * MM + j] = (t >= j) ? crow[j] : 0.f;
    }
  }
  __syncthreads();

  // ---- GH[m] = sum_{k>=m} G[k] * L[k][m] (fully unrolled, register-resident) ----
  float GH[MM][EPT];
#pragma unroll
  for (int m = 0; m < MM; ++m) {
    float lcol[MM];
#pragma unroll
    for (int k = 0; k < MM; ++k) lcol[k] = s_L[k * MM + m];
#pragma unroll
    for (int j = 0; j < EPT; ++j) {
      float s = 0.f;
#pragma unroll
      for (int k = 0; k < MM; ++k)
        if (k >= m) s = fmaf(G[k][j], lcol[k], s);
      GH[m][j] = s;
    }
  }
  // ---- publish iteration-invariant edge rows of GH ----
#pragma unroll
  for (int m = 0; m < MM; ++m) {
    s_gh7[t][m] = GH[m][7];
    s_gh0[t][m] = GH[m][0];
  }

  // ---- prologue: u,w,r for iteration 0 from x0 (duals are zero) ----
  float eta[EPT], tau[EPT];
#pragma unroll
  for (int j = 0; j < EPT; ++j) { eta[j] = 0.f; tau[j] = 0.f; }
  float u[EPT], w[EPT], r[EPT], pl0[EPT];
#pragma unroll
  for (int j = 0; j < EPT; ++j) {
    float xprev = (j == 0) ? xm1_0 : x[j - 1];
    float v = xprev - x[j];
    u[j] = copysignf(fmaxf(fabsf(v) - 1e-5f, 0.f), v);
    w[j] = fmaxf(x[j], 0.f);
    r[j] = bA[j] + 10.f * u[j] + 5.f * w[j];
  }
  {
    float zp[MM];
#pragma unroll
    for (int m = 0; m < MM; ++m) {
      float s = 0.f;
#pragma unroll
      for (int j = 0; j < EPT; ++j) s = fmaf(GH[m][j], r[j], s);
      zp[m] = wave_sum(s);
    }
    if (lane == 63) {
      *(float4*)&s_wq[0][wave][0] = make_float4(zp[0], zp[1], zp[2], zp[3]);
      *(float4*)&s_wq[0][wave][4] = make_float4(zp[4], zp[5], zp[6], zp[7]);
      s_wq[0][wave][8] = zp[8];
    }
  }
  solveM_pre(r, pl0, &s_sc[0][0], t);
  __syncthreads();

  // ---- ADMM iterations: ONE barrier each ----
#pragma unroll 1
  for (int it = 0; it < NIT; ++it) {
    const int rp = it & 1;
    // phase top: all LDS reads issue together
    float2 g[9];
    gather9(&s_sc[rp][0], t, g);
    float gh7r[MM], gh0r[MM];
    {
      const int tm = (t + NT - 1) & (NT - 1), tp = (t + 1) & (NT - 1);
#pragma unroll
      for (int m = 0; m < MM; ++m) { gh7r[m] = s_gh7[tm][m]; gh0r[m] = s_gh0[tp][m]; }
    }
    float zv = 0.f;
    if (lane < MM) {
#pragma unroll
      for (int wv = 0; wv < 8; ++wv) zv += s_wq[rp][wv][lane];
    }
    float z[MM];
#pragma unroll
    for (int m = 0; m < MM; ++m) z[m] = bcast_lane(zv, m);
    // finish solve -> p, then x = p - GH z
    float p[EPT];
    finish_own(g, pl0, p);
#pragma unroll
    for (int j = 0; j < EPT; ++j) {
      float s = p[j];
#pragma unroll
      for (int m = 0; m < MM; ++m) s = fmaf(-GH[m][j], z[m], s);
      x[j] = s;
    }
    if (it == NIT - 1) break;
    // reconstruct neighbor boundary values of x (bit-identical to their own)
    float xm1 = p7_prev(g);
#pragma unroll
    for (int m = 0; m < MM; ++m) xm1 = fmaf(-gh7r[m], z[m], xm1);
    float xp1 = p0_next(g);
#pragma unroll
    for (int m = 0; m < MM; ++m) xp1 = fmaf(-gh0r[m], z[m], xp1);
    // duals (u,w carried from previous phase's r-build)
#pragma unroll
    for (int j = 0; j < EPT - 1; ++j) {
      eta[j] = fmaf(10.f, (x[j + 1] - x[j]) - u[j], eta[j]);
      tau[j] = fmaf(5.f, x[j] - w[j], tau[j]);
    }
    eta[7] = fmaf(10.f, (xp1 - x[7]) - u[7], eta[7]);
    tau[7] = fmaf(5.f, x[7] - w[7], tau[7]);
    // u, w, r for next iteration
#pragma unroll
    for (int j = 0; j < EPT; ++j) {
      float xprev = (j == 0) ? xm1 : x[j - 1];
      float v = xprev - x[j] + eta[j] * 0.1f;
      u[j] = copysignf(fmaxf(fabsf(v) - 1e-5f, 0.f), v);
      w[j] = fmaxf(fmaf(tau[j], 0.2f, x[j]), 0.f);
      r[j] = bA[j] + 10.f * u[j] - eta[j] + 5.f * w[j] - tau[j];
    }
    // zeta partials + publish, scan seeds + publish (parity^1)
    float zp[MM];
#pragma unroll
    for (int m = 0; m < MM; ++m) {
      float s = 0.f;
#pragma unroll
      for (int j = 0; j < EPT; ++j) s = fmaf(GH[m][j], r[j], s);
      zp[m] = wave_sum(s);
    }
    if (lane == 63) {
      *(float4*)&s_wq[rp ^ 1][wave][0] = make_float4(zp[0], zp[1], zp[2], zp[3]);
      *(float4*)&s_wq[rp ^ 1][wave][4] = make_float4(zp[4], zp[5], zp[6], zp[7]);
      s_wq[rp ^ 1][wave][8] = zp[8];
    }
    solveM_pre(r, pl0, &s_sc[rp ^ 1][0], t);
    __syncthreads();                            // the ONLY barrier
  }

  // ---- output ----
  float4 o0, o1;
  o0.x = x[0]; o0.y = x[1]; o0.z = x[2]; o0.w = x[3];
  o1.x = x[4]; o1.y = x[5]; o1.z = x[6]; o1.w = x[7];
  *(float4*)(out + base) = o0;
  *(float4*)(out + base + 4) = o1;
}

extern "C" void kernel_launch(void* const* d_in, const int* in_sizes, int n_in,
                              void* d_out, int out_size, void* d_ws, size_t ws_size,
                              hipStream_t stream) {
  const float* target = (const float*)d_in[0];
  const float* A      = (const float*)d_in[1];
  const float* x0     = (const float*)d_in[2];
  admm_kernel<<<1, NT, 0, stream>>>(target, A, x0, (float*)d_out);
}